// Round 10
// baseline (948.456 us; speedup 1.0000x reference)
//
#include <hip/hip_runtime.h>
#include <hip/hip_cooperative_groups.h>
#include <math.h>

namespace cg = cooperative_groups;

#define N_NODES 100000
#define N_EDGES 1600000
#define LN_EPS 1e-5f
#define NORM_EPS 1e-12f
#define SCAN_TILE 1024
#define N_TILES 98                    // ceil(N_NODES / 1024)
#define NPAD (N_TILES * SCAN_TILE)    // 100352, memset-zeroed padding
#define ROWS_PER_BLOCK 32
#define N_ROWTILES (N_NODES / ROWS_PER_BLOCK)   // 3125, exact
#define WSTRIDE 66   // even (b64-aligned) and 2c+k -> 2-way banks (free)
#define NUM_CU 256   // MI355X [rocminfo]

// bf16 helpers (round-to-nearest-even)
__device__ __forceinline__ unsigned short f2bf(float f) {
    unsigned int u = __float_as_uint(f);
    u += 0x7FFFu + ((u >> 16) & 1u);
    return (unsigned short)(u >> 16);
}
__device__ __forceinline__ float bf2f(unsigned short h) {
    return __uint_as_float(((unsigned int)h) << 16);
}

// ---------------------------------------------------------------------------
// Persistent cooperative kernel.  All phases grid-stride; phases separated by
// grid.sync().  Collapses 6 dispatches -> 2 (memset + this), removes launch
// gaps, stages W into LDS once per block instead of once per row-tile, and
// keeps h16/s_dst warm in L2 into the gather phase.
// GEMM k-loop DELIBERATELY NOT UNROLLED (#pragma unroll 1): R5/R6 measured
// the unrolled version spilling acc[] at ANY VGPR budget (2.0/0.95 GB
// scratch writes).  No min-waves hint (R5: it's a VGPR cap -> spills).
// NO nontemporal hints (R9: neutral on loads, negative on scatter stores).
// ---------------------------------------------------------------------------
__global__ __launch_bounds__(256) void k_mega(
    const float* __restrict__ x, const float* __restrict__ W,
    const float* __restrict__ b, const float* __restrict__ a,
    const int* __restrict__ ei,
    int* __restrict__ counts, int* __restrict__ row_ptr,
    int* __restrict__ cursor, int* __restrict__ tiletot,
    int* __restrict__ dst_sorted,
    unsigned short* __restrict__ h16,
    float* __restrict__ s_src, float* __restrict__ s_dst,
    const float* __restrict__ ln_scale, const float* __restrict__ ln_bias,
    float* __restrict__ out)
{
    cg::grid_group grid = cg::this_grid();
    __shared__ float WL[64 * WSTRIDE];            // WL[c*66 + k] = W[c][k]
    __shared__ float xs[ROWS_PER_BLOCK * 64];
    __shared__ int wsum4[4];
    __shared__ int spref[N_TILES];

    const int tid  = threadIdx.x;
    const int lane = tid & 63;
    const int wv   = tid >> 6;
    const int gsz  = gridDim.x;
    const int gtid = blockIdx.x * 256 + tid;
    const int nthr = gsz * 256;

    // ================= phase 1: GEMM (h = xW^T + b -> bf16, scores) ========
    // W staged ONCE per block (vec4 reads, scalar conflict-free writes).
    for (int idx = tid * 4; idx < 64 * 64; idx += 256 * 4) {
        const float4 w = *(const float4*)(W + idx);
        const int c = idx >> 6, k = idx & 63;
        WL[c * WSTRIDE + k + 0] = w.x;
        WL[c * WSTRIDE + k + 1] = w.y;
        WL[c * WSTRIDE + k + 2] = w.z;
        WL[c * WSTRIDE + k + 3] = w.w;
    }
    const float bias = b[lane];
    const float asrc = a[(lane >> 3) * 16 + (lane & 7)];
    const float adst = a[(lane >> 3) * 16 + 8 + (lane & 7)];

    for (int t = blockIdx.x; t < N_ROWTILES; t += gsz) {
        __syncthreads();   // protects xs from previous iteration's readers
                           // (first iteration: doubles as the WL barrier)
        const int row0 = t * ROWS_PER_BLOCK;
        for (int idx = tid * 4; idx < ROWS_PER_BLOCK * 64; idx += 256 * 4)
            *(float4*)(xs + idx) = *(const float4*)(x + (size_t)row0 * 64 + idx);
        __syncthreads();

        float acc[8];
        #pragma unroll
        for (int r = 0; r < 8; ++r) acc[r] = bias;
        const int rbase = wv * 8;
        const float* wrow = WL + lane * WSTRIDE;
        const float* xrow = xs + rbase * 64;
        #pragma unroll 1   // DO NOT unroll: keeps live set small (see header)
        for (int kk = 0; kk < 64; kk += 4) {
            const float2 w01 = *(const float2*)(wrow + kk);
            const float2 w23 = *(const float2*)(wrow + kk + 2);
            #pragma unroll
            for (int r = 0; r < 8; ++r) {
                const float4 xq = *(const float4*)(xrow + r * 64 + kk);
                acc[r] += xq.x * w01.x + xq.y * w01.y + xq.z * w23.x + xq.w * w23.y;
            }
        }
        #pragma unroll
        for (int r = 0; r < 8; ++r) {
            const int row = row0 + rbase + r;
            const float v = acc[r];
            h16[(size_t)row * 64 + lane] = f2bf(v);
            float p = v * asrc, q = v * adst;
            p += __shfl_xor(p, 1);  q += __shfl_xor(q, 1);
            p += __shfl_xor(p, 2);  q += __shfl_xor(q, 2);
            p += __shfl_xor(p, 4);  q += __shfl_xor(q, 4);
            if ((lane & 7) == 0) {
                s_src[row * 8 + (lane >> 3)] = p;
                s_dst[row * 8 + (lane >> 3)] = q;
            }
        }
    }
    // ---- out-degree histogram (edge-stride; counts pre-zeroed by memset) --
    for (int e = gtid; e < N_EDGES; e += nthr)
        atomicAdd(&counts[ei[e]], 1);

    grid.sync();

    // ================= phase 2: scan A (98 tiles of 1024, int4 loads) ======
    // counts is padded+zeroed to NPAD, so unguarded int4 loads are safe.
    for (int t = blockIdx.x; t < N_TILES; t += gsz) {
        const int base = t * SCAN_TILE + tid * 4;
        const int4 v = *(const int4*)(counts + base);
        const int s = v.x + v.y + v.z + v.w;
        int sc = s;
        #pragma unroll
        for (int off = 1; off < 64; off <<= 1) {
            const int tt = __shfl_up(sc, off);
            if (lane >= off) sc += tt;
        }
        if (lane == 63) wsum4[wv] = sc;
        __syncthreads();
        int pre = 0;
        #pragma unroll
        for (int w = 0; w < 4; ++w) if (w < wv) pre += wsum4[w];
        const int excl = pre + sc - s;
        row_ptr[base + 0] = excl;                    // padded region: junk ok
        row_ptr[base + 1] = excl + v.x;
        row_ptr[base + 2] = excl + v.x + v.y;
        row_ptr[base + 3] = excl + v.x + v.y + v.z;
        if (tid == 255) tiletot[t] = pre + sc;       // block total
        __syncthreads();   // protect wsum4 for next tile
    }

    grid.sync();

    // ====== phase 3: scan B (redundant per-block) + add-back + cursor ======
    if (tid < 64) {
        int v0 = (tid < N_TILES) ? tiletot[tid] : 0;
        int s0 = v0;
        #pragma unroll
        for (int off = 1; off < 64; off <<= 1) {
            const int tt = __shfl_up(s0, off);
            if (tid >= off) s0 += tt;
        }
        if (tid < N_TILES) spref[tid] = s0 - v0;
        const int carry = __shfl(s0, 63);
        const int i2 = 64 + tid;
        int v1 = (i2 < N_TILES) ? tiletot[i2] : 0;
        int s1 = v1;
        #pragma unroll
        for (int off = 1; off < 64; off <<= 1) {
            const int tt = __shfl_up(s1, off);
            if (tid >= off) s1 += tt;
        }
        if (i2 < N_TILES) spref[i2] = carry + s1 - v1;
    }
    __syncthreads();
    for (int i = gtid; i < N_NODES; i += nthr) {
        const int r = row_ptr[i] + spref[i >> 10];
        row_ptr[i] = r;
        cursor[i]  = r;
    }
    if (gtid == 0) row_ptr[N_NODES] = N_EDGES;

    grid.sync();

    // ================= phase 4: CSR fill (edge-stride) =====================
    for (int e = gtid; e < N_EDGES; e += nthr) {
        const int src = ei[e];
        const int dst = ei[N_EDGES + e];
        const int slot = atomicAdd(&cursor[src], 1);
        dst_sorted[slot] = dst;
    }

    grid.sync();

    // ======= phase 5: gather + inline alpha + LN + L2-norm (wave/node) =====
    const int g   = lane >> 3;    // phase1: edge-in-chunk; phase2: head
    const int sub = lane & 7;     // phase1: head
    const int nwaves = gsz * 4;
    for (int i = blockIdx.x * 4 + wv; i < N_NODES; i += nwaves) {
        const int beg = row_ptr[i];
        const int end = row_ptr[i + 1];
        const float ssrc = s_src[i * 8 + sub];
        const float xres = x[(size_t)i * 64 + lane];

        float acc = 0.f;
        for (int chunk = beg; chunk < end; chunk += 8) {
            const int ne = min(8, end - chunk);
            // ---- cooperative alpha for 8 edges ----
            const int e = chunk + g;
            int de = 0;
            float sc = 0.f;
            if (e < end) {
                de = dst_sorted[e];
                sc = ssrc + s_dst[de * 8 + sub];
            }
            sc = (sc >= 0.f) ? sc : 0.2f * sc;
            float m = sc;
            m = fmaxf(m, __shfl_xor(m, 1));
            m = fmaxf(m, __shfl_xor(m, 2));
            m = fmaxf(m, __shfl_xor(m, 4));
            const float ex = __expf(sc - m);
            float su = ex;
            su += __shfl_xor(su, 1);
            su += __shfl_xor(su, 2);
            su += __shfl_xor(su, 4);
            const float alpha = ex * __builtin_amdgcn_rcpf(su);

            // ---- redistribute via shuffle, 8 independent h16 loads ----
            int   dv[8];
            float av[8];
            #pragma unroll
            for (int j = 0; j < 8; ++j) {
                if (j < ne) {
                    dv[j] = __shfl(de, j * 8);
                    av[j] = __shfl(alpha, j * 8 + g);
                }
            }
            unsigned short hv[8];
            #pragma unroll
            for (int j = 0; j < 8; ++j)
                if (j < ne) hv[j] = h16[(size_t)dv[j] * 64 + lane];
            #pragma unroll
            for (int j = 0; j < 8; ++j)
                if (j < ne) acc += av[j] * bf2f(hv[j]);
        }

        // epilogue: residual + LayerNorm + L2 normalize
        float v = acc + xres;
        float s = v;
        #pragma unroll
        for (int off = 1; off < 64; off <<= 1) s += __shfl_xor(s, off);
        const float mu = s * (1.f / 64.f);
        const float d = v - mu;
        float vs = d * d;
        #pragma unroll
        for (int off = 1; off < 64; off <<= 1) vs += __shfl_xor(vs, off);
        const float var = vs * (1.f / 64.f);
        float y = d * rsqrtf(var + LN_EPS) * ln_scale[lane] + ln_bias[lane];
        float ss = y * y;
        #pragma unroll
        for (int off = 1; off < 64; off <<= 1) ss += __shfl_xor(ss, off);
        const float norm = sqrtf(ss);
        out[(size_t)i * 64 + lane] = y / fmaxf(norm, NORM_EPS);
    }
}

// ---------------------------------------------------------------------------
extern "C" void kernel_launch(void* const* d_in, const int* in_sizes, int n_in,
                              void* d_out, int out_size, void* d_ws, size_t ws_size,
                              hipStream_t stream)
{
    const float* x        = (const float*)d_in[0];
    const int*   ei       = (const int*)d_in[1];
    const float* W        = (const float*)d_in[2];
    const float* b        = (const float*)d_in[3];
    const float* a        = (const float*)d_in[4];
    const float* ln_scale = (const float*)d_in[5];
    const float* ln_bias  = (const float*)d_in[6];
    float* out = (float*)d_out;

    char* ws = (char*)d_ws;
    size_t off = 0;
    auto alloc = [&](size_t bytes) {
        void* p = ws + off;
        off = (off + bytes + 255) & ~(size_t)255;
        return p;
    };
    unsigned short* h16 = (unsigned short*)alloc((size_t)N_NODES * 64 * 2);
    float* s_src      = (float*)alloc((size_t)N_NODES * 8 * 4);
    float* s_dst      = (float*)alloc((size_t)N_NODES * 8 * 4);
    int*   counts     = (int*)  alloc((size_t)NPAD * 4);          // zero-padded
    int*   row_ptr    = (int*)  alloc((size_t)(NPAD + 1) * 4);    // padded
    int*   cursor     = (int*)  alloc((size_t)N_NODES * 4);
    int*   tiletot    = (int*)  alloc((size_t)N_TILES * 4);
    int*   dst_sorted = (int*)  alloc((size_t)N_EDGES * 4);

    hipMemsetAsync(counts, 0, (size_t)NPAD * 4, stream);

    // Co-residency: query exact occupancy (LDS ~25.5 KB -> expect 4-6/CU).
    int maxBlk = 0;
    hipError_t err = hipOccupancyMaxActiveBlocksPerMultiprocessor(
        &maxBlk, (const void*)k_mega, 256, 0);
    if (err != hipSuccess || maxBlk < 1) maxBlk = 2;  // safe floor (LDS allows 6)
    const int grid = maxBlk * NUM_CU;

    void* args[] = {
        (void*)&x, (void*)&W, (void*)&b, (void*)&a, (void*)&ei,
        (void*)&counts, (void*)&row_ptr, (void*)&cursor, (void*)&tiletot,
        (void*)&dst_sorted, (void*)&h16, (void*)&s_src, (void*)&s_dst,
        (void*)&ln_scale, (void*)&ln_bias, (void*)&out
    };
    hipLaunchCooperativeKernel((const void*)k_mega, dim3(grid), dim3(256),
                               args, 0, stream);
}

// Round 11
// 331.931 us; speedup vs baseline: 2.8574x; 2.8574x over previous
//
#include <hip/hip_runtime.h>
#include <hip/hip_fp16.h>
#include <math.h>

#define N_NODES 100000
#define N_EDGES 1600000
#define LN_EPS 1e-5f
#define NORM_EPS 1e-12f
#define SCAN_TILE 1024
#define N_TILES ((N_NODES + SCAN_TILE - 1) / SCAN_TILE)   // 98
#define ROWS_PER_BLOCK 32
#define GEMM_BLOCKS (N_NODES / ROWS_PER_BLOCK)            // 3125, exact
#define WSTRIDE 66   // even (b64-aligned) and 2c+k -> 2-way banks (free)

// ---------------------------------------------------------------------------
// K1: h = x @ W^T + b (N x 64) -> fp16 (|h|~6 << 65504; 8x less quant error
// than bf16); per-node attn scores fp32; fused edge count (atomics AFTER the
// k-loop).  K-LOOP DELIBERATELY NOT UNROLLED (#pragma unroll 1): R5/R6
// measured the unrolled version spilling acc[] at ANY VGPR budget (2.0/0.95
// GB scratch writes).  No min-waves hint (R5: it's a VGPR cap -> spills).
// NO nontemporal hints (R9: neutral/negative).  NO cooperative launch (R10:
// grid.sync ~200us each on 8-XCD gfx950).
// ---------------------------------------------------------------------------
__global__ __launch_bounds__(256) void k_gemm(
    const float* __restrict__ x, const float* __restrict__ W,
    const float* __restrict__ b, const float* __restrict__ a,
    const int* __restrict__ ei, int* __restrict__ counts,
    __half* __restrict__ h16,
    float* __restrict__ s_src, float* __restrict__ s_dst)
{
    __shared__ float WL[64 * WSTRIDE];            // WL[c*66 + k] = W[c][k]
    __shared__ float xs[ROWS_PER_BLOCK * 64];
    const int tid  = threadIdx.x;
    const int lane = tid & 63;
    const int wv   = tid >> 6;

    for (int idx = tid * 4; idx < 64 * 64; idx += 256 * 4) {
        const float4 w = *(const float4*)(W + idx);
        const int c = idx >> 6, k = idx & 63;
        WL[c * WSTRIDE + k + 0] = w.x;
        WL[c * WSTRIDE + k + 1] = w.y;
        WL[c * WSTRIDE + k + 2] = w.z;
        WL[c * WSTRIDE + k + 3] = w.w;
    }
    const int row0 = blockIdx.x * ROWS_PER_BLOCK;
    for (int idx = tid * 4; idx < ROWS_PER_BLOCK * 64; idx += 256 * 4)
        *(float4*)(xs + idx) = *(const float4*)(x + (size_t)row0 * 64 + idx);
    __syncthreads();

    const float bias = b[lane];
    float acc[8];
    #pragma unroll
    for (int r = 0; r < 8; ++r) acc[r] = bias;

    const int rbase = wv * 8;
    const float* wrow = WL + lane * WSTRIDE;
    const float* xrow = xs + rbase * 64;
    #pragma unroll 1   // DO NOT unroll: keeps live set small (see header)
    for (int kk = 0; kk < 64; kk += 4) {
        const float2 w01 = *(const float2*)(wrow + kk);
        const float2 w23 = *(const float2*)(wrow + kk + 2);
        #pragma unroll
        for (int r = 0; r < 8; ++r) {
            const float4 xq = *(const float4*)(xrow + r * 64 + kk);
            acc[r] += xq.x * w01.x + xq.y * w01.y + xq.z * w23.x + xq.w * w23.y;
        }
    }

    // fused out-degree count: no __syncthreads after this point
    {
        const int e0 = blockIdx.x * 256 + tid;
        atomicAdd(&counts[ei[e0]], 1);
        atomicAdd(&counts[ei[e0 + GEMM_BLOCKS * 256]], 1);
    }

    const float asrc = a[(lane >> 3) * 16 + (lane & 7)];
    const float adst = a[(lane >> 3) * 16 + 8 + (lane & 7)];
    #pragma unroll
    for (int r = 0; r < 8; ++r) {
        const int row = row0 + rbase + r;
        const float v = acc[r];
        h16[(size_t)row * 64 + lane] = __float2half_rn(v);
        float p = v * asrc, q = v * adst;
        p += __shfl_xor(p, 1);  q += __shfl_xor(q, 1);
        p += __shfl_xor(p, 2);  q += __shfl_xor(q, 2);
        p += __shfl_xor(p, 4);  q += __shfl_xor(q, 4);
        if ((lane & 7) == 0) {
            s_src[row * 8 + (lane >> 3)] = p;
            s_dst[row * 8 + (lane >> 3)] = q;
        }
    }
}

// ---------------------------------------------------------------------------
// Scan stage 1: per-tile (1024) exclusive scan + tile totals.
// ---------------------------------------------------------------------------
__global__ __launch_bounds__(1024) void k_scan1(
    const int* __restrict__ counts, int* __restrict__ row_ptr,
    int* __restrict__ blksum)
{
    __shared__ int wsum[16];
    const int tid = threadIdx.x, lane = tid & 63, wv = tid >> 6;
    const int i = blockIdx.x * SCAN_TILE + tid;
    int v = (i < N_NODES) ? counts[i] : 0;
    int sc = v;
    #pragma unroll
    for (int off = 1; off < 64; off <<= 1) {
        int t = __shfl_up(sc, off);
        if (lane >= off) sc += t;
    }
    if (lane == 63) wsum[wv] = sc;
    __syncthreads();
    if (tid < 16) {
        int ws = wsum[tid];
        #pragma unroll
        for (int off = 1; off < 16; off <<= 1) {
            int t = __shfl_up(ws, off);
            if (tid >= off) ws += t;
        }
        wsum[tid] = ws;
    }
    __syncthreads();
    const int pref = wv ? wsum[wv - 1] : 0;
    if (i < N_NODES) row_ptr[i] = pref + sc - v;   // tile-local exclusive
    if (tid == 0) blksum[blockIdx.x] = wsum[15];
}

// ---------------------------------------------------------------------------
// Scan stages 2+3 fused: redundant 98-element scan per block, add-back,
// cursor init.
// ---------------------------------------------------------------------------
__global__ __launch_bounds__(256) void k_scan23(
    int* __restrict__ row_ptr, const int* __restrict__ blksum,
    int* __restrict__ cursor)
{
    __shared__ int spref[N_TILES];
    const int tid = threadIdx.x;
    if (tid < 64) {
        int v0 = (tid < N_TILES) ? blksum[tid] : 0;
        int s0 = v0;
        #pragma unroll
        for (int off = 1; off < 64; off <<= 1) {
            int t = __shfl_up(s0, off);
            if (tid >= off) s0 += t;
        }
        if (tid < N_TILES) spref[tid] = s0 - v0;
        int carry = __shfl(s0, 63);
        int i2 = 64 + tid;
        int v1 = (i2 < N_TILES) ? blksum[i2] : 0;
        int s1 = v1;
        #pragma unroll
        for (int off = 1; off < 64; off <<= 1) {
            int t = __shfl_up(s1, off);
            if (tid >= off) s1 += t;
        }
        if (i2 < N_TILES) spref[i2] = carry + s1 - v1;
    }
    __syncthreads();
    const int i = blockIdx.x * 256 + tid;
    if (i < N_NODES) {
        int r = row_ptr[i] + spref[i >> 10];
        row_ptr[i] = r;
        cursor[i] = r;
    }
    if (i == 0) row_ptr[N_NODES] = N_EDGES;
}

// ---------------------------------------------------------------------------
// Fill + alpha: one THREAD per edge; scatter dst (4 B) + 8-head softmax
// packed to fp16 (ONE 16 B store, half of R7's 32 B fp32 scatter which
// measured 300 MB traffic / 134 us).  alpha in [0,1]: fp16 rel err 0.05%.
// ---------------------------------------------------------------------------
__global__ __launch_bounds__(256) void k_fill_alpha(
    const int* __restrict__ ei, int* __restrict__ cursor,
    const float* __restrict__ s_src, const float* __restrict__ s_dst,
    int* __restrict__ dst_sorted, __half* __restrict__ alpha16)
{
    const int e = blockIdx.x * 256 + threadIdx.x;
    if (e >= N_EDGES) return;
    const int src = ei[e];
    const int dst = ei[N_EDGES + e];
    const int slot = atomicAdd(&cursor[src], 1);
    dst_sorted[slot] = dst;

    const float4 a0 = *(const float4*)(s_src + (size_t)src * 8);
    const float4 a1 = *(const float4*)(s_src + (size_t)src * 8 + 4);
    const float4 b0 = *(const float4*)(s_dst + (size_t)dst * 8);
    const float4 b1 = *(const float4*)(s_dst + (size_t)dst * 8 + 4);
    float sc[8] = {a0.x + b0.x, a0.y + b0.y, a0.z + b0.z, a0.w + b0.w,
                   a1.x + b1.x, a1.y + b1.y, a1.z + b1.z, a1.w + b1.w};
    float m = -1e30f;
    #pragma unroll
    for (int h = 0; h < 8; ++h) {
        sc[h] = (sc[h] >= 0.f) ? sc[h] : 0.2f * sc[h];
        m = fmaxf(m, sc[h]);
    }
    float sum = 0.f;
    #pragma unroll
    for (int h = 0; h < 8; ++h) { sc[h] = __expf(sc[h] - m); sum += sc[h]; }
    const float inv = 1.f / sum;
    unsigned int q[4];
    #pragma unroll
    for (int j = 0; j < 4; ++j) {
        const unsigned short lo = __half_as_ushort(__float2half_rn(sc[2*j]   * inv));
        const unsigned short hi = __half_as_ushort(__float2half_rn(sc[2*j+1] * inv));
        q[j] = (unsigned int)lo | ((unsigned int)hi << 16);
    }
    uint4 pk = make_uint4(q[0], q[1], q[2], q[3]);
    *(uint4*)(alpha16 + (size_t)slot * 8) = pk;    // 16 B aligned: slot*16 B
}

// ---------------------------------------------------------------------------
// Gather + epilogue: one wave per node; slim loop (~8-10 instrs/edge):
// sequential dst + alpha16 streams, random 128 B h16 row, FMA.
// (R8's inline-alpha variant measured ~50 instrs/edge via VALUBusy math.)
// ---------------------------------------------------------------------------
__global__ __launch_bounds__(256) void k_gather(
    const int* __restrict__ row_ptr, const int* __restrict__ dst_sorted,
    const __half* __restrict__ alpha16, const __half* __restrict__ h16,
    const float* __restrict__ x, const float* __restrict__ ln_scale,
    const float* __restrict__ ln_bias, float* __restrict__ out)
{
    const int i = blockIdx.x * 4 + (threadIdx.x >> 6);
    if (i >= N_NODES) return;
    const int lane = threadIdx.x & 63;
    const int head = lane >> 3;

    const int beg = row_ptr[i];
    const int end = row_ptr[i + 1];
    const float xres = x[(size_t)i * 64 + lane];

    float acc = 0.f;
    int e = beg;
    for (; e + 3 < end; e += 4) {
        const int d0 = dst_sorted[e];
        const int d1 = dst_sorted[e + 1];
        const int d2 = dst_sorted[e + 2];
        const int d3 = dst_sorted[e + 3];
        const float al0 = __half2float(alpha16[(size_t)(e + 0) * 8 + head]);
        const float al1 = __half2float(alpha16[(size_t)(e + 1) * 8 + head]);
        const float al2 = __half2float(alpha16[(size_t)(e + 2) * 8 + head]);
        const float al3 = __half2float(alpha16[(size_t)(e + 3) * 8 + head]);
        const float h0 = __half2float(h16[(size_t)d0 * 64 + lane]);
        const float h1 = __half2float(h16[(size_t)d1 * 64 + lane]);
        const float h2 = __half2float(h16[(size_t)d2 * 64 + lane]);
        const float h3 = __half2float(h16[(size_t)d3 * 64 + lane]);
        acc += al0 * h0 + al1 * h1 + al2 * h2 + al3 * h3;
    }
    for (; e < end; ++e)
        acc += __half2float(alpha16[(size_t)e * 8 + head]) *
               __half2float(h16[(size_t)dst_sorted[e] * 64 + lane]);

    // epilogue: residual + LayerNorm + L2 normalize
    float v = acc + xres;
    float s = v;
    #pragma unroll
    for (int off = 1; off < 64; off <<= 1) s += __shfl_xor(s, off);
    const float mu = s * (1.f / 64.f);
    const float d = v - mu;
    float vs = d * d;
    #pragma unroll
    for (int off = 1; off < 64; off <<= 1) vs += __shfl_xor(vs, off);
    const float var = vs * (1.f / 64.f);
    float y = d * rsqrtf(var + LN_EPS) * ln_scale[lane] + ln_bias[lane];
    float ss = y * y;
    #pragma unroll
    for (int off = 1; off < 64; off <<= 1) ss += __shfl_xor(ss, off);
    const float norm = sqrtf(ss);
    out[(size_t)i * 64 + lane] = y / fmaxf(norm, NORM_EPS);
}

// ---------------------------------------------------------------------------
extern "C" void kernel_launch(void* const* d_in, const int* in_sizes, int n_in,
                              void* d_out, int out_size, void* d_ws, size_t ws_size,
                              hipStream_t stream)
{
    const float* x        = (const float*)d_in[0];
    const int*   ei       = (const int*)d_in[1];
    const float* W        = (const float*)d_in[2];
    const float* b        = (const float*)d_in[3];
    const float* a        = (const float*)d_in[4];
    const float* ln_scale = (const float*)d_in[5];
    const float* ln_bias  = (const float*)d_in[6];
    float* out = (float*)d_out;

    char* ws = (char*)d_ws;
    size_t off = 0;
    auto alloc = [&](size_t bytes) {
        void* p = ws + off;
        off = (off + bytes + 255) & ~(size_t)255;
        return p;
    };
    __half* h16       = (__half*)alloc((size_t)N_NODES * 64 * 2);
    float* s_src      = (float*) alloc((size_t)N_NODES * 8 * 4);
    float* s_dst      = (float*) alloc((size_t)N_NODES * 8 * 4);
    int*   counts     = (int*)   alloc((size_t)N_NODES * 4);
    int*   row_ptr    = (int*)   alloc((size_t)(N_NODES + 1) * 4);
    int*   cursor     = (int*)   alloc((size_t)N_NODES * 4);
    int*   blksum     = (int*)   alloc((size_t)N_TILES * 4);
    int*   dst_sorted = (int*)   alloc((size_t)N_EDGES * 4);
    __half* alpha16   = (__half*)alloc((size_t)N_EDGES * 8 * 2);

    hipMemsetAsync(counts, 0, (size_t)N_NODES * 4, stream);

    k_gemm      <<<GEMM_BLOCKS, 256, 0, stream>>>(x, W, b, a, ei, counts,
                                                  h16, s_src, s_dst);
    k_scan1     <<<N_TILES, 1024, 0, stream>>>(counts, row_ptr, blksum);
    k_scan23    <<<(N_NODES + 255) / 256, 256, 0, stream>>>(row_ptr, blksum, cursor);
    k_fill_alpha<<<(N_EDGES + 255) / 256, 256, 0, stream>>>(ei, cursor, s_src, s_dst,
                                                            dst_sorted, alpha16);
    k_gather    <<<(N_NODES + 3) / 4,     256, 0, stream>>>(row_ptr, dst_sorted,
                                                            alpha16, h16, x,
                                                            ln_scale, ln_bias, out);
}